// Round 9
// baseline (177.721 us; speedup 1.0000x reference)
//
#include <hip/hip_runtime.h>
#include <math.h>

// ---------------------------------------------------------------------------
// HyperbolicInfoNCE on MI355X — Round 9: R6 GEMM + fused finalize + 3-deep
// occupancy.
//
// Journal lessons baked in:
//   R5: NO device-scope fences in per-block hot path (L2 wb/inv storm).
//   R5/R7: compiler refuses deep explicit register pipelines — spills
//          (R7: 126MB scratch traffic). Keep R6's simple loop.
//   R6: ownership restructure (wave = 64 rows x 4 col-tiles, consecutive
//       blocks share B-chunk) fixed the latency wall: 147->58.8us gemm.
//   R7: fence-free atomic finalize protocol verified correct (absmax 0).
//   R8: direct fp32 GEMM loads are 4B-aligned (stride 129) -> 4x load
//       instructions; bf16 staging is what provides aligned dwordx4 frags.
//       Single-kernel experiment: fixed harness overhead ~43us.
// This round: R6 GEMM + R7 finalize fusion + __launch_bounds__(256,3) to go
// 2 -> 3 blocks/CU (arch regs must fit ~106; spill tripwire = WRITE_SIZE).
// ---------------------------------------------------------------------------

#define BDIM   8192
#define K_IN   129
#define K_PAD  160      // 5 * 32
#define BK     32
#define NKT    (K_PAD / BK)   // 5
#define CTILES 4              // 64-col tiles per wave
#define NBLK   1024
#define KQ     (K_PAD / 4)    // 40

typedef __bf16  bf16x8 __attribute__((ext_vector_type(8)));
typedef float   f32x4  __attribute__((ext_vector_type(4)));

// ws layout (bytes): A, B, then rs | cp[4] | dg contiguous (zeroed together)
#define OFF_A    0u
#define OFF_B    (BDIM * K_PAD * 2u)                  // 2,621,440
#define OFF_RS   (2u * BDIM * K_PAD * 2u)             // 5,242,880
#define OFF_CP   (OFF_RS + BDIM * 4u)
#define OFF_DG   (OFF_CP + 4u * BDIM * 4u)
#define OFF_CNT  (OFF_DG + BDIM * 4u)

// ---- hardware transcendentals (v_sqrt_f32 / v_log_f32 / v_exp_f32) ----
__device__ __forceinline__ float fast_sqrt(float x) {
#if __has_builtin(__builtin_amdgcn_sqrtf)
    return __builtin_amdgcn_sqrtf(x);
#else
    return sqrtf(x);
#endif
}
__device__ __forceinline__ float fast_log2(float x) {
#if __has_builtin(__builtin_amdgcn_logf)
    return __builtin_amdgcn_logf(x);       // log base 2
#else
    return __log2f(x);
#endif
}
__device__ __forceinline__ float fast_exp2(float x) {
#if __has_builtin(__builtin_amdgcn_exp2f)
    return __builtin_amdgcn_exp2f(x);      // 2^x
#else
    extern "C" __device__ float __ocml_native_exp2_f32(float);
    return __ocml_native_exp2_f32(x);
#endif
}

__device__ __forceinline__ unsigned short f2bf_rne(float f) {
    unsigned int u = __float_as_uint(f);
    u += 0x7FFFu + ((u >> 16) & 1u);   // round-to-nearest-even
    return (unsigned short)(u >> 16);
}

// ---------------------------------------------------------------------------
// Kernel 1: fp32 -> bf16 (4 elems/thread, ushort4 stores), K zero-padded
// 129->160, Lorentz metric folded into A (negate column 0 of z1). Also
// zeroes rs + 4 col replicas + diag (6*BDIM contiguous floats) and cnt.
// ---------------------------------------------------------------------------
__global__ __launch_bounds__(256) void convert_kernel(
    const float* __restrict__ z1, const float* __restrict__ z2,
    unsigned short* __restrict__ A, unsigned short* __restrict__ B,
    float* __restrict__ zero6, unsigned int* __restrict__ cnt)
{
    int idx = blockIdx.x * 256 + threadIdx.x;    // [0, BDIM*KQ)
    if (idx == 0) *cnt = 0u;
    if (idx < 6 * BDIM) zero6[idx] = 0.f;
    if (idx >= BDIM * KQ) return;
    int r = idx / KQ;
    int k = (idx - r * KQ) * 4;                  // 0,4,...,156
    float va[4], vb[4];
    #pragma unroll
    for (int u = 0; u < 4; ++u) {
        int c = k + u;
        va[u] = 0.f; vb[u] = 0.f;
        if (c < K_IN) {
            va[u] = z1[r * K_IN + c];
            vb[u] = z2[r * K_IN + c];
            if (c == 0) va[u] = -va[u];          // Lorentz metric
        }
    }
    ushort4 ha, hb;
    ha.x = f2bf_rne(va[0]); ha.y = f2bf_rne(va[1]);
    ha.z = f2bf_rne(va[2]); ha.w = f2bf_rne(va[3]);
    hb.x = f2bf_rne(vb[0]); hb.y = f2bf_rne(vb[1]);
    hb.z = f2bf_rne(vb[2]); hb.w = f2bf_rne(vb[3]);
    *(ushort4*)&A[r * K_PAD + k] = ha;
    *(ushort4*)&B[r * K_PAD + k] = hb;
}

// ---------------------------------------------------------------------------
// Kernel 2: strip-GEMM (R6 loop shape) + fused acosh/exp epilogue + fused
// last-block finalize (R7 protocol).
//   grid = 1024: bid = chunk*64 + strip  (consecutive blocks share B-chunk)
//   block: rows [strip*128,+128) x cols [chunk*512,+512); 4 waves 2x2;
//   wave: 64 rows x 4 col-tiles of 64x64 (4x4 MFMA 16x16x32 each).
//   fragment layouts (guide-verified, m89/m91):
//     A/B: elem [m=lane&15][k=(lane>>4)*8 + j]
//     C/D: elem [row=(lane>>4)*4 + reg][col=lane&15]
// ---------------------------------------------------------------------------
__global__ __launch_bounds__(256, 3) void gemm_epilogue_kernel(
    const unsigned short* __restrict__ A, const unsigned short* __restrict__ B,
    float* __restrict__ row_sum, float* __restrict__ col_part,
    float* __restrict__ diag, unsigned int* __restrict__ cnt,
    float* __restrict__ out)
{
    const int t    = threadIdx.x;
    const int lane = t & 63;
    const int wave = t >> 6;
    const int quad = lane >> 4;
    const int l16  = lane & 15;

    const int strip = blockIdx.x & 63;
    const int chunk = blockIdx.x >> 6;
    const int wr      = (wave >> 1) * 64;
    const int rowBase = strip * 128 + wr;
    const int colWave = chunk * 512 + (wave & 1) * 256;

    const unsigned short* Abase = A + (rowBase + l16) * K_PAD + quad * 8;
    float* colRep = col_part + (strip & 3) * BDIM;

    float rowp[4][4] = {};   // persistent across col-tiles

    for (int ct = 0; ct < CTILES; ++ct) {
        const int colBase = colWave + ct * 64;
        const unsigned short* Bbase = B + (colBase + l16) * K_PAD + quad * 8;

        f32x4 acc[4][4] = {};
        #pragma unroll
        for (int kt = 0; kt < NKT; ++kt) {
            bf16x8 af[4], bfr[4];
            #pragma unroll
            for (int i = 0; i < 4; ++i) {
                af[i]  = *(const bf16x8*)(Abase + i * 16 * K_PAD + kt * BK);
                bfr[i] = *(const bf16x8*)(Bbase + i * 16 * K_PAD + kt * BK);
            }
            #pragma unroll
            for (int i = 0; i < 4; ++i)
                #pragma unroll
                for (int j = 0; j < 4; ++j)
                    acc[i][j] = __builtin_amdgcn_mfma_f32_16x16x32_bf16(
                                    af[i], bfr[j], acc[i][j], 0, 0, 0);
        }

        // ---- fused epilogue for this 64x64 tile ----
        // u = x + sqrt(x^2-1), x = max(-inner, 1+1e-6)
        // exp(sims) = exp2(-14.2857142857 * log2(u))
        // sims      = -(ln2/0.07) * log2(u)
        const bool diagTile = (colBase == rowBase);
        float colp[4] = {0.f, 0.f, 0.f, 0.f};

        #pragma unroll
        for (int i = 0; i < 4; ++i) {
            #pragma unroll
            for (int j = 0; j < 4; ++j) {
                #pragma unroll
                for (int reg = 0; reg < 4; ++reg) {
                    float inner = acc[i][j][reg];
                    float x = fmaxf(-inner, 1.000001f);
                    float sq = fast_sqrt(__builtin_fmaf(x, x, -1.0f));
                    float l2u = fast_log2(x + sq);
                    float e = fast_exp2(-14.285714285714286f * l2u);
                    rowp[i][reg] += e;
                    colp[j]      += e;
                    if (diagTile && i == j && (quad * 4 + reg) == l16) {
                        int R = rowBase + i * 16 + quad * 4 + reg;
                        atomicAdd(&diag[R], -9.902102579427789f * l2u);
                    }
                }
            }
        }
        // col sums: reduce across quads, one atomic per col
        #pragma unroll
        for (int j = 0; j < 4; ++j) {
            float v = colp[j];
            v += __shfl_xor(v, 16);
            v += __shfl_xor(v, 32);
            if (quad == 0)
                atomicAdd(&colRep[colBase + j * 16 + l16], v);
        }
    }

    // row sums (accumulated over all 4 col-tiles): reduce across quad lanes
    #pragma unroll
    for (int i = 0; i < 4; ++i) {
        #pragma unroll
        for (int reg = 0; reg < 4; ++reg) {
            float v = rowp[i][reg];
            v += __shfl_xor(v, 1);
            v += __shfl_xor(v, 2);
            v += __shfl_xor(v, 4);
            v += __shfl_xor(v, 8);
            if (l16 == 0)
                atomicAdd(&row_sum[rowBase + i * 16 + quad * 4 + reg], v);
        }
    }

    // ---- fused finalize: atomic-only protocol, NO fences (R7-verified) ----
    __builtin_amdgcn_s_waitcnt(0);
    __shared__ unsigned int lastFlag;
    __shared__ float part[4];
    __syncthreads();
    if (t == 0) {
        unsigned int old = atomicAdd(cnt, 1u);
        lastFlag = (old == NBLK - 1u) ? 1u : 0u;
    }
    __syncthreads();
    if (lastFlag) {
        const float LN2_HALF = 0.34657359027997264f;  // 0.5 * ln2
        float a = 0.f;
        for (int b = t; b < BDIM; b += 256) {
            float r  = __hip_atomic_load(&row_sum[b], __ATOMIC_RELAXED,
                                         __HIP_MEMORY_SCOPE_AGENT);
            float c0 = __hip_atomic_load(&col_part[b], __ATOMIC_RELAXED,
                                         __HIP_MEMORY_SCOPE_AGENT);
            float c1 = __hip_atomic_load(&col_part[b + BDIM], __ATOMIC_RELAXED,
                                         __HIP_MEMORY_SCOPE_AGENT);
            float c2 = __hip_atomic_load(&col_part[b + 2 * BDIM], __ATOMIC_RELAXED,
                                         __HIP_MEMORY_SCOPE_AGENT);
            float c3 = __hip_atomic_load(&col_part[b + 3 * BDIM], __ATOMIC_RELAXED,
                                         __HIP_MEMORY_SCOPE_AGENT);
            float d  = __hip_atomic_load(&diag[b], __ATOMIC_RELAXED,
                                         __HIP_MEMORY_SCOPE_AGENT);
            a += LN2_HALF * (fast_log2(r) + fast_log2(c0 + c1 + c2 + c3)) - d;
        }
        #pragma unroll
        for (int m = 1; m < 64; m <<= 1) a += __shfl_xor(a, m);
        if (lane == 0) part[wave] = a;
        __syncthreads();
        if (t == 0)
            out[0] = (part[0] + part[1] + part[2] + part[3])
                     * (1.0f / (float)BDIM);
    }
}

// ---------------------------------------------------------------------------
extern "C" void kernel_launch(void* const* d_in, const int* in_sizes, int n_in,
                              void* d_out, int out_size, void* d_ws, size_t ws_size,
                              hipStream_t stream)
{
    const float* z1 = (const float*)d_in[0];
    const float* z2 = (const float*)d_in[1];
    float* out = (float*)d_out;

    char* ws = (char*)d_ws;
    unsigned short* A  = (unsigned short*)(ws + OFF_A);
    unsigned short* B  = (unsigned short*)(ws + OFF_B);
    float* row_sum     = (float*)(ws + OFF_RS);
    float* col_part    = (float*)(ws + OFF_CP);
    float* diag        = (float*)(ws + OFF_DG);
    unsigned int* cnt  = (unsigned int*)(ws + OFF_CNT);

    convert_kernel<<<(BDIM * KQ + 255) / 256, 256, 0, stream>>>(
        z1, z2, A, B, row_sum /* rs|cp|dg contiguous */, cnt);

    gemm_epilogue_kernel<<<NBLK, 256, 0, stream>>>(
        A, B, row_sum, col_part, diag, cnt, out);
}

// Round 10
// 167.422 us; speedup vs baseline: 1.0615x; 1.0615x over previous
//
#include <hip/hip_runtime.h>
#include <math.h>

// ---------------------------------------------------------------------------
// HyperbolicInfoNCE on MI355X — Round 10: LDS ping-pong B-prefetch via
// global_load_lds + hoisted A fragments + fused finalize.
//
// Journal lessons baked in:
//   R5:  NO device-scope fences in per-block hot path (L2 wb/inv storm).
//   R5/R7/R9: register pressure is untouchable — compiler sinks manual
//        prefetch (R5), spills rotating pipelines (R7, 126MB scratch),
//        spills under launch_bounds(256,3) (R9, 72MB scratch). (256,2) + the
//        R6 loop is the stable point.
//   R6:  ownership restructure (wave = 64 rows x 4 col-tiles) -> 58.8us gemm.
//   R7/R9: fence-free atomic finalize protocol verified correct twice.
//   R8:  bf16 staging arrays are load-bearing (aligned dwordx4); fixed
//        harness overhead ~43us.
// This round attacks the ~90k cyc/SIMD load-latency stall with the one
// prefetch mechanism that does NOT consume VGPRs: global_load_lds. B tiles
// for ct+1 stream into the ping-pong LDS buffer while ct computes; the
// compiler's mandatory vmcnt(0)-before-s_barrier becomes the prefetch wait.
// A fragments (loop-invariant across ct) are hoisted into registers once.
// ---------------------------------------------------------------------------

#define BDIM   8192
#define K_IN   129
#define K_PAD  160      // 5 * 32
#define BK     32
#define NKT    5
#define CTILES 4              // 64-col tiles per wave
#define NBLK   1024
#define KQ     (K_PAD / 4)    // 40
#define SLAB   8192           // one kt-slab: 128 staged cols x 32 k x 2B
#define STAGEB (4 * SLAB)     // kt 0..3 staged; kt=4 direct-global

typedef __bf16  bf16x8 __attribute__((ext_vector_type(8)));
typedef float   f32x4  __attribute__((ext_vector_type(4)));

// ws layout (bytes): A, B, then rs | cp[4] | dg contiguous + cnt
#define OFF_A    0u
#define OFF_B    (BDIM * K_PAD * 2u)                  // 2,621,440
#define OFF_RS   (2u * BDIM * K_PAD * 2u)             // 5,242,880
#define OFF_CP   (OFF_RS + BDIM * 4u)
#define OFF_DG   (OFF_CP + 4u * BDIM * 4u)
#define OFF_CNT  (OFF_DG + BDIM * 4u)

// ---- hardware transcendentals ----
__device__ __forceinline__ float fast_sqrt(float x) {
#if __has_builtin(__builtin_amdgcn_sqrtf)
    return __builtin_amdgcn_sqrtf(x);
#else
    return sqrtf(x);
#endif
}
__device__ __forceinline__ float fast_log2(float x) {
#if __has_builtin(__builtin_amdgcn_logf)
    return __builtin_amdgcn_logf(x);       // log base 2
#else
    return __log2f(x);
#endif
}
__device__ __forceinline__ float fast_exp2(float x) {
#if __has_builtin(__builtin_amdgcn_exp2f)
    return __builtin_amdgcn_exp2f(x);      // 2^x
#else
    extern "C" __device__ float __ocml_native_exp2_f32(float);
    return __ocml_native_exp2_f32(x);
#endif
}

__device__ __forceinline__ unsigned short f2bf_rne(float f) {
    unsigned int u = __float_as_uint(f);
    u += 0x7FFFu + ((u >> 16) & 1u);   // round-to-nearest-even
    return (unsigned short)(u >> 16);
}

// async global->LDS, 16B/lane: LDS dest = (uniform) ldsptr + lane*16
__device__ __forceinline__ void gload_lds16(const void* g, void* l) {
    __builtin_amdgcn_global_load_lds(
        (const __attribute__((address_space(1))) unsigned int*)g,
        (__attribute__((address_space(3))) unsigned int*)l, 16, 0, 0);
}

// ---------------------------------------------------------------------------
// Kernel 1: fp32 -> bf16 (ushort4 stores), K zero-padded 129->160, metric
// folded into A (negate col 0 of z1). Zeroes rs|cp|dg (6*BDIM) and cnt.
// ---------------------------------------------------------------------------
__global__ __launch_bounds__(256) void convert_kernel(
    const float* __restrict__ z1, const float* __restrict__ z2,
    unsigned short* __restrict__ A, unsigned short* __restrict__ B,
    float* __restrict__ zero6, unsigned int* __restrict__ cnt)
{
    int idx = blockIdx.x * 256 + threadIdx.x;    // [0, BDIM*KQ)
    if (idx == 0) *cnt = 0u;
    if (idx < 6 * BDIM) zero6[idx] = 0.f;
    if (idx >= BDIM * KQ) return;
    int r = idx / KQ;
    int k = (idx - r * KQ) * 4;                  // 0,4,...,156
    float va[4], vb[4];
    #pragma unroll
    for (int u = 0; u < 4; ++u) {
        int c = k + u;
        va[u] = 0.f; vb[u] = 0.f;
        if (c < K_IN) {
            va[u] = z1[r * K_IN + c];
            vb[u] = z2[r * K_IN + c];
            if (c == 0) va[u] = -va[u];          // Lorentz metric
        }
    }
    ushort4 ha, hb;
    ha.x = f2bf_rne(va[0]); ha.y = f2bf_rne(va[1]);
    ha.z = f2bf_rne(va[2]); ha.w = f2bf_rne(va[3]);
    hb.x = f2bf_rne(vb[0]); hb.y = f2bf_rne(vb[1]);
    hb.z = f2bf_rne(vb[2]); hb.w = f2bf_rne(vb[3]);
    *(ushort4*)&A[r * K_PAD + k] = ha;
    *(ushort4*)&B[r * K_PAD + k] = hb;
}

// ---------------------------------------------------------------------------
// Kernel 2: strip-GEMM, B via LDS ping-pong prefetch, A hoisted in regs,
// fused acosh/exp epilogue + fused last-block finalize.
//   grid = 1024: bid = chunk*64 + strip; block rows [strip*128,+128) x cols
//   [chunk*512,+512); 4 waves 2x2; wave: 64 rows x 4 col-tiles of 64x64.
//   B stage layout (per buffer): [kt 0..3][ri 0..127][32 k]  (8KB slabs);
//   ri<64 -> gcol = chunk*512 + ct*64 + ri   (waves 0/2)
//   ri>=64 -> gcol = chunk*512 + 256 + ct*64 + (ri-64)  (waves 1/3)
//   Wave w stages slab kt=w: 8 x gload_lds16 covering 128 rows.
//   fragment layouts (guide-verified, m89/m91):
//     A/B: elem [m=lane&15][k=(lane>>4)*8 + j]
//     C/D: elem [row=(lane>>4)*4 + reg][col=lane&15]
// ---------------------------------------------------------------------------
__global__ __launch_bounds__(256, 2) void gemm_epilogue_kernel(
    const unsigned short* __restrict__ A, const unsigned short* __restrict__ B,
    float* __restrict__ row_sum, float* __restrict__ col_part,
    float* __restrict__ diag, unsigned int* __restrict__ cnt,
    float* __restrict__ out)
{
    __shared__ __align__(16) unsigned char Bstage[2][STAGEB];  // 64 KB
    __shared__ unsigned int lastFlag;
    __shared__ float part[4];

    const int t    = threadIdx.x;
    const int lane = t & 63;
    const int wave = t >> 6;
    const int quad = lane >> 4;
    const int l16  = lane & 15;

    const int strip = blockIdx.x & 63;
    const int chunk = blockIdx.x >> 6;
    const int wr      = (wave >> 1) * 64;
    const int rowBase = strip * 128 + wr;
    const int colWave = chunk * 512 + (wave & 1) * 256;

    float* colRep = col_part + (strip & 3) * BDIM;

    // ---- hoist all 20 A fragments (loop-invariant across ct) ----
    const unsigned short* Abase = A + (rowBase + l16) * K_PAD + quad * 8;
    bf16x8 aF[NKT][4];
    #pragma unroll
    for (int kt = 0; kt < NKT; ++kt)
        #pragma unroll
        for (int i = 0; i < 4; ++i)
            aF[kt][i] = *(const bf16x8*)(Abase + i * 16 * K_PAD + kt * BK);

    // ---- per-lane global source addresses for B staging (this wave stages
    //      slab kt=wave; 8 wave-loads of 1KB cover ri 0..127) ----
    const unsigned char* Bby = (const unsigned char*)B;
    const unsigned char* gA[8];
    #pragma unroll
    for (int wp = 0; wp < 8; ++wp) {
        int gcol = chunk * 512 + (wp >> 2) * 256 + (wp & 3) * 16 + (lane >> 2);
        gA[wp] = Bby + gcol * (K_PAD * 2) + wave * 64 + (lane & 3) * 16;
    }

    // stage ct=0 into buffer 0
    {
        unsigned char* sd = Bstage[0] + wave * SLAB;
        #pragma unroll
        for (int wp = 0; wp < 8; ++wp)
            gload_lds16(gA[wp], sd + wp * 1024);
    }
    __syncthreads();   // compiler emits vmcnt(0) drain -> buffer 0 ready

    float rowp[4][4] = {};

    #pragma unroll
    for (int ct = 0; ct < CTILES; ++ct) {
        // prefetch ct+1 into the other buffer (issued right after barrier)
        if (ct < CTILES - 1) {
            unsigned char* sd = Bstage[(ct + 1) & 1] + wave * SLAB;
            const int coff = (ct + 1) * 64 * K_PAD * 2;   // +64 cols
            #pragma unroll
            for (int wp = 0; wp < 8; ++wp)
                gload_lds16(gA[wp] + coff, sd + wp * 1024);
        }

        const int colBase = colWave + ct * 64;
        const unsigned char* sb = Bstage[ct & 1];
        const int ldsRow = (wave & 1) * 64 + l16;          // ri of this lane

        f32x4 acc[4][4] = {};

        // kt=4 B fragments direct from global (issue early for overlap)
        bf16x8 b4[4];
        #pragma unroll
        for (int j = 0; j < 4; ++j)
            b4[j] = *(const bf16x8*)(B + (colBase + j * 16 + l16) * K_PAD
                                     + 4 * BK + quad * 8);

        #pragma unroll
        for (int kt = 0; kt < 4; ++kt) {
            bf16x8 bfr[4];
            #pragma unroll
            for (int j = 0; j < 4; ++j)
                bfr[j] = *(const bf16x8*)(sb + kt * SLAB
                                          + (ldsRow + j * 16) * 64 + quad * 16);
            #pragma unroll
            for (int i = 0; i < 4; ++i)
                #pragma unroll
                for (int j = 0; j < 4; ++j)
                    acc[i][j] = __builtin_amdgcn_mfma_f32_16x16x32_bf16(
                                    aF[kt][i], bfr[j], acc[i][j], 0, 0, 0);
        }
        #pragma unroll
        for (int i = 0; i < 4; ++i)
            #pragma unroll
            for (int j = 0; j < 4; ++j)
                acc[i][j] = __builtin_amdgcn_mfma_f32_16x16x32_bf16(
                                aF[4][i], b4[j], acc[i][j], 0, 0, 0);

        // ---- fused epilogue for this 64x64 tile ----
        // u = x + sqrt(x^2-1), x = max(-inner, 1+1e-6)
        // exp(sims) = exp2(-14.2857142857 * log2(u))
        // sims      = -(ln2/0.07) * log2(u)
        const bool diagTile = (colBase == rowBase);
        float colp[4] = {0.f, 0.f, 0.f, 0.f};

        #pragma unroll
        for (int i = 0; i < 4; ++i) {
            #pragma unroll
            for (int j = 0; j < 4; ++j) {
                #pragma unroll
                for (int reg = 0; reg < 4; ++reg) {
                    float inner = acc[i][j][reg];
                    float x = fmaxf(-inner, 1.000001f);
                    float sq = fast_sqrt(__builtin_fmaf(x, x, -1.0f));
                    float l2u = fast_log2(x + sq);
                    float e = fast_exp2(-14.285714285714286f * l2u);
                    rowp[i][reg] += e;
                    colp[j]      += e;
                    if (diagTile && i == j && (quad * 4 + reg) == l16) {
                        int R = rowBase + i * 16 + quad * 4 + reg;
                        atomicAdd(&diag[R], -9.902102579427789f * l2u);
                    }
                }
            }
        }
        // col sums: reduce across quads, one atomic per col
        #pragma unroll
        for (int j = 0; j < 4; ++j) {
            float v = colp[j];
            v += __shfl_xor(v, 16);
            v += __shfl_xor(v, 32);
            if (quad == 0)
                atomicAdd(&colRep[colBase + j * 16 + l16], v);
        }

        // barrier: (a) all waves done reading buf[ct&1] before it's restaged,
        // (b) vmcnt(0) drain completes the ct+1 prefetch.
        if (ct < CTILES - 1) __syncthreads();
    }

    // row sums (accumulated over all 4 col-tiles): reduce across quad lanes
    #pragma unroll
    for (int i = 0; i < 4; ++i) {
        #pragma unroll
        for (int reg = 0; reg < 4; ++reg) {
            float v = rowp[i][reg];
            v += __shfl_xor(v, 1);
            v += __shfl_xor(v, 2);
            v += __shfl_xor(v, 4);
            v += __shfl_xor(v, 8);
            if (l16 == 0)
                atomicAdd(&row_sum[rowBase + i * 16 + quad * 4 + reg], v);
        }
    }

    // ---- fused finalize: atomic-only protocol, NO fences (R7/R9-verified) ----
    __builtin_amdgcn_s_waitcnt(0);
    __syncthreads();
    if (t == 0) {
        unsigned int old = atomicAdd(cnt, 1u);
        lastFlag = (old == NBLK - 1u) ? 1u : 0u;
    }
    __syncthreads();
    if (lastFlag) {
        const float LN2_HALF = 0.34657359027997264f;  // 0.5 * ln2
        float a = 0.f;
        for (int b = t; b < BDIM; b += 256) {
            float r  = __hip_atomic_load(&row_sum[b], __ATOMIC_RELAXED,
                                         __HIP_MEMORY_SCOPE_AGENT);
            float c0 = __hip_atomic_load(&col_part[b], __ATOMIC_RELAXED,
                                         __HIP_MEMORY_SCOPE_AGENT);
            float c1 = __hip_atomic_load(&col_part[b + BDIM], __ATOMIC_RELAXED,
                                         __HIP_MEMORY_SCOPE_AGENT);
            float c2 = __hip_atomic_load(&col_part[b + 2 * BDIM], __ATOMIC_RELAXED,
                                         __HIP_MEMORY_SCOPE_AGENT);
            float c3 = __hip_atomic_load(&col_part[b + 3 * BDIM], __ATOMIC_RELAXED,
                                         __HIP_MEMORY_SCOPE_AGENT);
            float d  = __hip_atomic_load(&diag[b], __ATOMIC_RELAXED,
                                         __HIP_MEMORY_SCOPE_AGENT);
            a += LN2_HALF * (fast_log2(r) + fast_log2(c0 + c1 + c2 + c3)) - d;
        }
        #pragma unroll
        for (int m = 1; m < 64; m <<= 1) a += __shfl_xor(a, m);
        if (lane == 0) part[wave] = a;
        __syncthreads();
        if (t == 0)
            out[0] = (part[0] + part[1] + part[2] + part[3])
                     * (1.0f / (float)BDIM);
    }
}

// ---------------------------------------------------------------------------
extern "C" void kernel_launch(void* const* d_in, const int* in_sizes, int n_in,
                              void* d_out, int out_size, void* d_ws, size_t ws_size,
                              hipStream_t stream)
{
    const float* z1 = (const float*)d_in[0];
    const float* z2 = (const float*)d_in[1];
    float* out = (float*)d_out;

    char* ws = (char*)d_ws;
    unsigned short* A  = (unsigned short*)(ws + OFF_A);
    unsigned short* B  = (unsigned short*)(ws + OFF_B);
    float* row_sum     = (float*)(ws + OFF_RS);
    float* col_part    = (float*)(ws + OFF_CP);
    float* diag        = (float*)(ws + OFF_DG);
    unsigned int* cnt  = (unsigned int*)(ws + OFF_CNT);

    convert_kernel<<<(BDIM * KQ + 255) / 256, 256, 0, stream>>>(
        z1, z2, A, B, row_sum /* rs|cp|dg contiguous */, cnt);

    gemm_epilogue_kernel<<<NBLK, 256, 0, stream>>>(
        A, B, row_sum, col_part, diag, cnt, out);
}

// Round 11
// 164.499 us; speedup vs baseline: 1.0804x; 1.0178x over previous
//
#include <hip/hip_runtime.h>
#include <math.h>

// ---------------------------------------------------------------------------
// HyperbolicInfoNCE on MI355X — Round 11: LDS B ping-pong WITHOUT the A-hoist
// (the un-confounded version of R10).
//
// Journal lessons baked in:
//   R5:  NO device-scope fences in per-block hot path (L2 wb/inv storm).
//   R5/R7/R9/R10: register pressure is untouchable — compiler sinks manual
//        prefetch (R5), spills rotating pipelines (R7, 126MB scratch), spills
//        under launch_bounds(256,3) (R9, 72MB), spilled the 80-VGPR A-hoist
//        (R10, 105MB). R6's per-kt loads + (256,2) is the stable point.
//   R6:  ownership restructure (wave = 64 rows x 4 col-tiles) -> 58.8us gemm.
//   R7/R9/R10: fence-free atomic finalize protocol verified correct 3x.
//   R8:  bf16 staging arrays are load-bearing; fixed harness overhead ~43us.
//   R10: global_load_lds staging address math verified correct (absmax 0);
//        perf was masked by the A-hoist spills -> retry without it.
// Structure: B tiles for ct+1 stream into the ping-pong LDS buffer via
// global_load_lds (zero VGPR cost) AFTER the current tile's ds_reads/MFMAs,
// hidden behind the ~2800cyc transcendental epilogue; the end-of-ct
// __syncthreads' mandatory vmcnt(0) is the prefetch wait. A loads stay
// per-kt from global (R6 shape, warm L2).
// ---------------------------------------------------------------------------

#define BDIM   8192
#define K_IN   129
#define K_PAD  160      // 5 * 32
#define BK     32
#define CTILES 4              // 64-col tiles per wave
#define NBLK   1024
#define KQ     (K_PAD / 4)    // 40
#define SLAB   8192           // one kt-slab: 128 staged cols x 32 k x 2B
#define STAGEB (4 * SLAB)     // kt 0..3 staged; kt=4 direct-global

typedef __bf16  bf16x8 __attribute__((ext_vector_type(8)));
typedef float   f32x4  __attribute__((ext_vector_type(4)));

// ws layout (bytes): A, B, then rs | cp[4] | dg contiguous + cnt
#define OFF_A    0u
#define OFF_B    (BDIM * K_PAD * 2u)                  // 2,621,440
#define OFF_RS   (2u * BDIM * K_PAD * 2u)             // 5,242,880
#define OFF_CP   (OFF_RS + BDIM * 4u)
#define OFF_DG   (OFF_CP + 4u * BDIM * 4u)
#define OFF_CNT  (OFF_DG + BDIM * 4u)

// ---- hardware transcendentals ----
__device__ __forceinline__ float fast_sqrt(float x) {
#if __has_builtin(__builtin_amdgcn_sqrtf)
    return __builtin_amdgcn_sqrtf(x);
#else
    return sqrtf(x);
#endif
}
__device__ __forceinline__ float fast_log2(float x) {
#if __has_builtin(__builtin_amdgcn_logf)
    return __builtin_amdgcn_logf(x);       // log base 2
#else
    return __log2f(x);
#endif
}
__device__ __forceinline__ float fast_exp2(float x) {
#if __has_builtin(__builtin_amdgcn_exp2f)
    return __builtin_amdgcn_exp2f(x);      // 2^x
#else
    extern "C" __device__ float __ocml_native_exp2_f32(float);
    return __ocml_native_exp2_f32(x);
#endif
}

__device__ __forceinline__ unsigned short f2bf_rne(float f) {
    unsigned int u = __float_as_uint(f);
    u += 0x7FFFu + ((u >> 16) & 1u);   // round-to-nearest-even
    return (unsigned short)(u >> 16);
}

// async global->LDS, 16B/lane: per-lane global source, LDS dest = base+lane*16
__device__ __forceinline__ void gload_lds16(const void* g, void* l) {
    __builtin_amdgcn_global_load_lds(
        (const __attribute__((address_space(1))) unsigned int*)g,
        (__attribute__((address_space(3))) unsigned int*)l, 16, 0, 0);
}

// ---------------------------------------------------------------------------
// Kernel 1: fp32 -> bf16 (ushort4 stores), K zero-padded 129->160, metric
// folded into A (negate col 0 of z1). Zeroes rs|cp|dg (6*BDIM) and cnt.
// ---------------------------------------------------------------------------
__global__ __launch_bounds__(256) void convert_kernel(
    const float* __restrict__ z1, const float* __restrict__ z2,
    unsigned short* __restrict__ A, unsigned short* __restrict__ B,
    float* __restrict__ zero6, unsigned int* __restrict__ cnt)
{
    int idx = blockIdx.x * 256 + threadIdx.x;    // [0, BDIM*KQ)
    if (idx == 0) *cnt = 0u;
    if (idx < 6 * BDIM) zero6[idx] = 0.f;
    if (idx >= BDIM * KQ) return;
    int r = idx / KQ;
    int k = (idx - r * KQ) * 4;                  // 0,4,...,156
    float va[4], vb[4];
    #pragma unroll
    for (int u = 0; u < 4; ++u) {
        int c = k + u;
        va[u] = 0.f; vb[u] = 0.f;
        if (c < K_IN) {
            va[u] = z1[r * K_IN + c];
            vb[u] = z2[r * K_IN + c];
            if (c == 0) va[u] = -va[u];          // Lorentz metric
        }
    }
    ushort4 ha, hb;
    ha.x = f2bf_rne(va[0]); ha.y = f2bf_rne(va[1]);
    ha.z = f2bf_rne(va[2]); ha.w = f2bf_rne(va[3]);
    hb.x = f2bf_rne(vb[0]); hb.y = f2bf_rne(vb[1]);
    hb.z = f2bf_rne(vb[2]); hb.w = f2bf_rne(vb[3]);
    *(ushort4*)&A[r * K_PAD + k] = ha;
    *(ushort4*)&B[r * K_PAD + k] = hb;
}

// ---------------------------------------------------------------------------
// Kernel 2: strip-GEMM; A per-kt from global (R6 shape), B from LDS ping-pong
// (global_load_lds, staged one ct ahead); fused acosh/exp epilogue + fused
// last-block finalize.
//   grid = 1024: bid = chunk*64 + strip; block rows [strip*128,+128) x cols
//   [chunk*512,+512); 4 waves 2x2; wave: 64 rows x 4 col-tiles of 64x64.
//   B stage layout (per buffer): [kt 0..3][ri 0..127][64B k-slab]
//     ri<64 -> gcol = chunk*512 + ct*64 + ri        (waves 0/2 read)
//     ri>=64 -> gcol = chunk*512 + 256 + ct*64 + ri-64  (waves 1/3 read)
//   Wave w stages slab kt=w: 8 x gload_lds16 (1KB each) covering 128 cols.
//   fragment layouts (guide-verified, m89/m91):
//     A/B: elem [m=lane&15][k=(lane>>4)*8 + j]
//     C/D: elem [row=(lane>>4)*4 + reg][col=lane&15]
// ---------------------------------------------------------------------------
__global__ __launch_bounds__(256, 2) void gemm_epilogue_kernel(
    const unsigned short* __restrict__ A, const unsigned short* __restrict__ B,
    float* __restrict__ row_sum, float* __restrict__ col_part,
    float* __restrict__ diag, unsigned int* __restrict__ cnt,
    float* __restrict__ out)
{
    __shared__ __align__(16) unsigned char Bstage[2][STAGEB];  // 64 KB
    __shared__ unsigned int lastFlag;
    __shared__ float part[4];

    const int t    = threadIdx.x;
    const int lane = t & 63;
    const int wave = t >> 6;
    const int quad = lane >> 4;
    const int l16  = lane & 15;

    const int strip = blockIdx.x & 63;
    const int chunk = blockIdx.x >> 6;
    const int wr      = (wave >> 1) * 64;
    const int rowBase = strip * 128 + wr;
    const int colWave = chunk * 512 + (wave & 1) * 256;

    const unsigned short* Abase = A + (rowBase + l16) * K_PAD + quad * 8;
    float* colRep = col_part + (strip & 3) * BDIM;

    // per-lane global source addresses for B staging (wave stages slab kt=wave)
    const unsigned char* Bby = (const unsigned char*)B;
    const unsigned char* gA[8];
    #pragma unroll
    for (int wp = 0; wp < 8; ++wp) {
        int gcol = chunk * 512 + (wp >> 2) * 256 + (wp & 3) * 16 + (lane >> 2);
        gA[wp] = Bby + gcol * (K_PAD * 2) + wave * 64 + (lane & 3) * 16;
    }

    // stage ct=0 into buffer 0
    {
        unsigned char* sd = Bstage[0] + wave * SLAB;
        #pragma unroll
        for (int wp = 0; wp < 8; ++wp)
            gload_lds16(gA[wp], sd + wp * 1024);
    }
    __syncthreads();   // vmcnt(0) drain -> buffer 0 ready

    float rowp[4][4] = {};

    #pragma unroll
    for (int ct = 0; ct < CTILES; ++ct) {
        const int colBase = colWave + ct * 64;
        const unsigned char* sb = Bstage[ct & 1];
        const int ldsRow = (wave & 1) * 64 + l16;          // ri of this lane

        f32x4 acc[4][4] = {};

        // kt = 0..3: A per-kt from global (R6 shape), B from LDS
        #pragma unroll
        for (int kt = 0; kt < 4; ++kt) {
            bf16x8 af[4], bfr[4];
            #pragma unroll
            for (int i = 0; i < 4; ++i) {
                af[i]  = *(const bf16x8*)(Abase + i * 16 * K_PAD + kt * BK);
                bfr[i] = *(const bf16x8*)(sb + kt * SLAB
                                          + (ldsRow + i * 16) * 64 + quad * 16);
            }
            #pragma unroll
            for (int i = 0; i < 4; ++i)
                #pragma unroll
                for (int j = 0; j < 4; ++j)
                    acc[i][j] = __builtin_amdgcn_mfma_f32_16x16x32_bf16(
                                    af[i], bfr[j], acc[i][j], 0, 0, 0);
        }
        // kt = 4: both A and B direct from global
        {
            bf16x8 af4[4], b4[4];
            #pragma unroll
            for (int i = 0; i < 4; ++i) {
                af4[i] = *(const bf16x8*)(Abase + i * 16 * K_PAD + 4 * BK);
                b4[i]  = *(const bf16x8*)(B + (colBase + i * 16 + l16) * K_PAD
                                          + 4 * BK + quad * 8);
            }
            #pragma unroll
            for (int i = 0; i < 4; ++i)
                #pragma unroll
                for (int j = 0; j < 4; ++j)
                    acc[i][j] = __builtin_amdgcn_mfma_f32_16x16x32_bf16(
                                    af4[i], b4[j], acc[i][j], 0, 0, 0);
        }

        // prefetch ct+1 into the other buffer — issued AFTER this tile's
        // ds_reads (so conservative LDS-alias waits land before the prefetch,
        // not before the reads) and hidden behind the epilogue below; the
        // end-of-ct barrier's vmcnt(0) completes it.
        if (ct < CTILES - 1) {
            unsigned char* sd = Bstage[(ct + 1) & 1] + wave * SLAB;
            const int coff = (ct + 1) * 64 * K_PAD * 2;   // +64 cols
            #pragma unroll
            for (int wp = 0; wp < 8; ++wp)
                gload_lds16(gA[wp] + coff, sd + wp * 1024);
        }

        // ---- fused epilogue for this 64x64 tile ----
        // u = x + sqrt(x^2-1), x = max(-inner, 1+1e-6)
        // exp(sims) = exp2(-14.2857142857 * log2(u))
        // sims      = -(ln2/0.07) * log2(u)
        const bool diagTile = (colBase == rowBase);
        float colp[4] = {0.f, 0.f, 0.f, 0.f};

        #pragma unroll
        for (int i = 0; i < 4; ++i) {
            #pragma unroll
            for (int j = 0; j < 4; ++j) {
                #pragma unroll
                for (int reg = 0; reg < 4; ++reg) {
                    float inner = acc[i][j][reg];
                    float x = fmaxf(-inner, 1.000001f);
                    float sq = fast_sqrt(__builtin_fmaf(x, x, -1.0f));
                    float l2u = fast_log2(x + sq);
                    float e = fast_exp2(-14.285714285714286f * l2u);
                    rowp[i][reg] += e;
                    colp[j]      += e;
                    if (diagTile && i == j && (quad * 4 + reg) == l16) {
                        int R = rowBase + i * 16 + quad * 4 + reg;
                        atomicAdd(&diag[R], -9.902102579427789f * l2u);
                    }
                }
            }
        }
        // col sums: reduce across quads, one atomic per col
        #pragma unroll
        for (int j = 0; j < 4; ++j) {
            float v = colp[j];
            v += __shfl_xor(v, 16);
            v += __shfl_xor(v, 32);
            if (quad == 0)
                atomicAdd(&colRep[colBase + j * 16 + l16], v);
        }

        // barrier: all waves done reading buf[ct&1]; vmcnt(0) drain completes
        // the ct+1 prefetch.
        if (ct < CTILES - 1) __syncthreads();
    }

    // row sums (accumulated over all 4 col-tiles): reduce across quad lanes
    #pragma unroll
    for (int i = 0; i < 4; ++i) {
        #pragma unroll
        for (int reg = 0; reg < 4; ++reg) {
            float v = rowp[i][reg];
            v += __shfl_xor(v, 1);
            v += __shfl_xor(v, 2);
            v += __shfl_xor(v, 4);
            v += __shfl_xor(v, 8);
            if (l16 == 0)
                atomicAdd(&row_sum[rowBase + i * 16 + quad * 4 + reg], v);
        }
    }

    // ---- fused finalize: atomic-only protocol, NO fences (verified 3x) ----
    __builtin_amdgcn_s_waitcnt(0);
    __syncthreads();
    if (t == 0) {
        unsigned int old = atomicAdd(cnt, 1u);
        lastFlag = (old == NBLK - 1u) ? 1u : 0u;
    }
    __syncthreads();
    if (lastFlag) {
        const float LN2_HALF = 0.34657359027997264f;  // 0.5 * ln2
        float a = 0.f;
        for (int b = t; b < BDIM; b += 256) {
            float r  = __hip_atomic_load(&row_sum[b], __ATOMIC_RELAXED,
                                         __HIP_MEMORY_SCOPE_AGENT);
            float c0 = __hip_atomic_load(&col_part[b], __ATOMIC_RELAXED,
                                         __HIP_MEMORY_SCOPE_AGENT);
            float c1 = __hip_atomic_load(&col_part[b + BDIM], __ATOMIC_RELAXED,
                                         __HIP_MEMORY_SCOPE_AGENT);
            float c2 = __hip_atomic_load(&col_part[b + 2 * BDIM], __ATOMIC_RELAXED,
                                         __HIP_MEMORY_SCOPE_AGENT);
            float c3 = __hip_atomic_load(&col_part[b + 3 * BDIM], __ATOMIC_RELAXED,
                                         __HIP_MEMORY_SCOPE_AGENT);
            float d  = __hip_atomic_load(&diag[b], __ATOMIC_RELAXED,
                                         __HIP_MEMORY_SCOPE_AGENT);
            a += LN2_HALF * (fast_log2(r) + fast_log2(c0 + c1 + c2 + c3)) - d;
        }
        #pragma unroll
        for (int m = 1; m < 64; m <<= 1) a += __shfl_xor(a, m);
        if (lane == 0) part[wave] = a;
        __syncthreads();
        if (t == 0)
            out[0] = (part[0] + part[1] + part[2] + part[3])
                     * (1.0f / (float)BDIM);
    }
}

// ---------------------------------------------------------------------------
extern "C" void kernel_launch(void* const* d_in, const int* in_sizes, int n_in,
                              void* d_out, int out_size, void* d_ws, size_t ws_size,
                              hipStream_t stream)
{
    const float* z1 = (const float*)d_in[0];
    const float* z2 = (const float*)d_in[1];
    float* out = (float*)d_out;

    char* ws = (char*)d_ws;
    unsigned short* A  = (unsigned short*)(ws + OFF_A);
    unsigned short* B  = (unsigned short*)(ws + OFF_B);
    float* row_sum     = (float*)(ws + OFF_RS);
    float* col_part    = (float*)(ws + OFF_CP);
    float* diag        = (float*)(ws + OFF_DG);
    unsigned int* cnt  = (unsigned int*)(ws + OFF_CNT);

    convert_kernel<<<(BDIM * KQ + 255) / 256, 256, 0, stream>>>(
        z1, z2, A, B, row_sum /* rs|cp|dg contiguous */, cnt);

    gemm_epilogue_kernel<<<NBLK, 256, 0, stream>>>(
        A, B, row_sum, col_part, diag, cnt, out);
}